// Round 8
// baseline (153.418 us; speedup 1.0000x reference)
//
#include <hip/hip_runtime.h>
#include <hip/hip_bf16.h>
#include <stdint.h>

typedef __attribute__((ext_vector_type(8))) short short8;
typedef __attribute__((ext_vector_type(16))) float f32x16;

// ---------------- ws layout (bytes) ----------------
// Xpad granules (16B = 8 channels): [b(8)][cb(8)][slot(4)][y(66)][x(66)]
//   slot = channel-granule within cb (plain, no swizzle)
#define XP_BYTES   17842176
#define XP_PAD     1024
#define OFF_W9     (XP_BYTES + XP_PAD)            // 17,843,200
#define W9_BYTES   (8*9*256*32*2)                 // 1,179,648
#define OFF_BIAS   (OFF_W9 + W9_BYTES)

__device__ __forceinline__ short f2bf(float f) {
  __hip_bfloat16 h = __float2bfloat16(f);
  return *reinterpret_cast<short*>(&h);
}

__device__ __forceinline__ void gl_lds16(const void* g, void* l) {
  __builtin_amdgcn_global_load_lds(
      (const __attribute__((address_space(1))) void*)g,
      (__attribute__((address_space(3))) void*)l, 16, 0, 0);
}

// Fused prep: blocks [0,256) weight prep (one per o); [256,4480) pad rows.
__global__ void k_prep(const float* __restrict__ X,
                       const float* __restrict__ core1,
                       const float* __restrict__ core2,
                       const float* __restrict__ core3,
                       const float* __restrict__ convw,
                       const float* __restrict__ convb,
                       short* __restrict__ Xp,
                       short* __restrict__ W9, float* __restrict__ bias) {
  if (blockIdx.x < 256) {
    // ---------------- weights ----------------
    __shared__ float H2s[1024];   // [u(16)][j(8)][k(8)]
    __shared__ float red[256];
    const int o = blockIdx.x, c = threadIdx.x;
    const int a = o >> 6, c2 = (o >> 3) & 7, d = o & 7;
#pragma unroll
    for (int p = 0; p < 4; ++p) {
      int idx = c + (p << 8);
      int k = idx & 7, j = (idx >> 3) & 7, u = idx >> 6;
      float s = 0.f;
#pragma unroll
      for (int v = 0; v < 16; ++v)
        s += core2[(c2 * 16 + v) * 128 + u * 8 + j] * core3[d * 128 + v * 8 + k];
      H2s[idx] = s;
    }
    __syncthreads();
    const int i = c >> 6, j = (c >> 3) & 7, k = c & 7;
    float Wr[16];
#pragma unroll
    for (int r = 0; r < 16; ++r) Wr[r] = 0.f;
    for (int u = 0; u < 16; ++u) {
      float h = H2s[u * 64 + j * 8 + k];
      const float* c1 = core1 + (a * 16 + u) * 64 + i;
#pragma unroll
      for (int r = 0; r < 16; ++r) Wr[r] += c1[r * 4] * h;
    }
    // W9 layout (plain, no swizzle): [cb][t][o(256)][g(4)][8] ; c = cb*32+g*8+pos
    const int cb = c >> 5, cl = c & 31;
#pragma unroll
    for (int t = 0; t < 9; ++t) {
      float s = 0.f;
#pragma unroll
      for (int r = 0; r < 16; ++r) s += Wr[r] * convw[r * 9 + t];
      W9[((size_t)((cb * 9 + t) * 256 + o)) * 32 + cl] = f2bf(s);
    }
    float s = 0.f;
#pragma unroll
    for (int r = 0; r < 16; ++r) s += Wr[r] * convb[r];
    red[c] = s;
    __syncthreads();
    for (int st = 128; st > 0; st >>= 1) {
      if (c < st) red[c] += red[c + st];
      __syncthreads();
    }
    if (c == 0) bias[o] = red[0];
    return;
  }
  // ---------------- pad+transpose (LDS-staged row, slot-major layout) ------
  const int p = blockIdx.x - 256;
  const int cb = p / 528, rem = p % 528;
  const int b = rem / 66, yp = rem % 66;
  const int t = threadIdx.x;
  const short8 z = (short8){0, 0, 0, 0, 0, 0, 0, 0};
  // dst granule for linear id g_ in [0,264): slot=g_/66, x=g_%66
  const size_t reg0 = (size_t)(b * 8 + cb) * 4;   // slot-region base /66/66
  if (yp == 0 || yp == 65) {
    {
      const int slot = t / 66, x = t % 66;
      *(short8*)(Xp + (((reg0 + slot) * 66 + yp) * 66 + x) * 8) = z;
    }
    if (t < 8) {
      const int g_ = 256 + t, slot = g_ / 66, x = g_ % 66;
      *(short8*)(Xp + (((reg0 + slot) * 66 + yp) * 66 + x) * 8) = z;
    }
    return;
  }
  __shared__ __align__(16) short Ls[264 * 8];   // one padded row, slot-major
  *(short8*)&Ls[t * 8] = z;
  if (t < 8) *(short8*)&Ls[(256 + t) * 8] = z;
  __syncthreads();
  const int x = t & 63, sub = t >> 6, xp = x + 1, y = yp - 1;
  const float* src = X + ((size_t)(b * 256 + cb * 32 + sub * 8) * 64 + y) * 64 + x;
  short8 v;
#pragma unroll
  for (int k = 0; k < 8; ++k) v[k] = f2bf(src[(size_t)k * 4096]);
  *(short8*)&Ls[(sub * 66 + xp) * 8] = v;   // slot = sub (plain)
  __syncthreads();
  {
    const int slot = t / 66, xc = t % 66;
    *(short8*)(Xp + (((reg0 + slot) * 66 + yp) * 66 + xc) * 8) =
        *(const short8*)&Ls[t * 8];
  }
  if (t < 8) {
    const int g_ = 256 + t, slot = g_ / 66, xc = g_ % 66;
    *(short8*)(Xp + (((reg0 + slot) * 66 + yp) * 66 + xc) * 8) =
        *(const short8*)&Ls[g_ * 8];
  }
}

// main GEMM, 32x32x16 MFMA: out[b,o,h,w] = bias[o] + sum_{c,t} K9*Xpad
// Wave = 2h x 64o x 32x (acc 2x2 f32x16); block = 8 waves = 8h x 64o x 64x.
// Grid (8,4,8) = 256 = 1/CU, 2 waves/SIMD. Halved MFMA instruction count vs
// 16x16x32 (4608/CU) + 17% better pipe rate; LDS reads/FLOP also halved.
// B-reads: 32 lanes x 16B contiguous (slot-major layout) -> conflict-free.
// A-frags from global W9 (L1-resident 36KB/cb), loaded per kh-half (18 b128)
// BEFORE each stage half so af waits are counted vmcnt (stage in flight).
__global__ __launch_bounds__(512, 1) void k_gemm(
    const short* __restrict__ Xp, const short* __restrict__ W9,
    const float* __restrict__ bias, float* __restrict__ out) {
  // [buf][slot(4) x 11264B]: 10 rows x 66 x staged per slot (+junk tail)
  __shared__ __align__(16) short XL[2][22528];   // 2 x 45,056 B

  const int tid  = threadIdx.x;
  const int lane = tid & 63;
  const int wv   = tid >> 6;           // 8 waves
  const int l31  = lane & 31;
  const int h5   = lane >> 5;          // k-half within K=16
  const int hp   = wv >> 1;            // h-pair 0..3
  const int xh   = wv & 1;             // x-half 0..1
  const int h0    = blockIdx.x << 3;   // 8 output rows / block
  const int oBase = blockIdx.y << 6;   // 64 out-channels / block
  const int b     = blockIdx.z;
  const int x0w   = xh << 5;           // wave x base (padded col = x0w+l31+dx)

  // per-thread bases
  // B (LDS, shorts): slot=(2kh+h5); row=hp*2+xr; x=x0w+l31+dx
  const int bof0 = (h5) * 5632 + ((hp * 132) + x0w + l31) * 8;        // kh=0
  const int bof1 = (2 + h5) * 5632 + ((hp * 132) + x0w + l31) * 8;    // kh=1
  // A (global W9, shorts): ((cb*9+t)*256 + oBase+io*32+l31)*32 + kh*16 + h5*8
  const int wbase = (oBase + l31) * 32 + h5 * 8;

  f32x16 acc[2][2];    // [rr][io]
#pragma unroll
  for (int rr = 0; rr < 2; ++rr)
#pragma unroll
    for (int io = 0; io < 2; ++io)
#pragma unroll
      for (int r = 0; r < 16; ++r) acc[rr][io][r] = 0.f;

  // stage: 44 chunks of 1KB (4 slots x 11); chunk (slot,i) covers granules
  // [h0*66 + 64i, +64) of the slot run (tail over-read lands in junk rows)
#define STG(CB, BUF, QLO, QHI)                                                \
  {                                                                           \
    _Pragma("unroll 1")                                                       \
    for (int q = (QLO) + wv; q < (QHI); q += 8) {                             \
      const int slot = q / 11, i = q % 11;                                    \
      const short* src = Xp +                                                 \
          ((((size_t)(b * 8 + (CB)) * 4 + slot) * 66 + h0) * 66               \
           + (i << 6) + lane) * 8;                                            \
      gl_lds16(src, &XL[BUF][slot * 5632 + (i << 9) + (lane << 3)]);          \
    }                                                                         \
  }

  STG(0, 0, 0, 44);   // prologue

  for (int cb = 0; cb < 8; ++cb) {
    const short* Wc = W9 + cb * 73728 + wbase;
    short8 af[9][2];
    // af(kh0): before the barrier -> its wait folds into the barrier drain
#pragma unroll
    for (int t = 0; t < 9; ++t)
#pragma unroll
      for (int io = 0; io < 2; ++io)
        af[t][io] = *(const short8*)&Wc[t * 8192 + (io << 10)];
    __builtin_amdgcn_sched_barrier(0);

    __syncthreads();   // XL[cb&1] ready (staged during cb-1)

    if (cb < 7) STG(cb + 1, (cb + 1) & 1, 0, 22);   // stage half A
    __builtin_amdgcn_sched_barrier(0);

    const short* XLc = &XL[cb & 1][0];
    short8 bfr[2][4];

#define LOADS(SET, BOF, DX)                                                   \
  {                                                                           \
    _Pragma("unroll")                                                         \
    for (int xr = 0; xr < 4; ++xr)                                            \
      bfr[SET][xr] = *(const short8*)&XLc[(BOF) + (xr * 66 + (DX)) * 8];      \
  }

#define MM(SET, DX)                                                           \
  {                                                                           \
    __builtin_amdgcn_s_setprio(1);                                            \
    _Pragma("unroll")                                                         \
    for (int dy = 0; dy < 3; ++dy)                                            \
      _Pragma("unroll")                                                       \
      for (int rr = 0; rr < 2; ++rr)                                          \
        _Pragma("unroll")                                                     \
        for (int io = 0; io < 2; ++io)                                        \
          acc[rr][io] = __builtin_amdgcn_mfma_f32_32x32x16_bf16(              \
              af[dy * 3 + (DX)][io], bfr[SET][rr + dy], acc[rr][io], 0, 0, 0);\
    __builtin_amdgcn_s_setprio(0);                                            \
  }

    // ---- kh = 0 ----
    LOADS(0, bof0, 0);
    LOADS(1, bof0, 1); __builtin_amdgcn_sched_barrier(0); MM(0, 0);
    LOADS(0, bof0, 2); __builtin_amdgcn_sched_barrier(0); MM(1, 1);
    __builtin_amdgcn_sched_barrier(0);                    MM(0, 2);

    // ---- af(kh1), then stage half B (af wait = counted vmcnt) ----
#pragma unroll
    for (int t = 0; t < 9; ++t)
#pragma unroll
      for (int io = 0; io < 2; ++io)
        af[t][io] = *(const short8*)&Wc[16 + t * 8192 + (io << 10)];
    __builtin_amdgcn_sched_barrier(0);
    if (cb < 7) STG(cb + 1, (cb + 1) & 1, 22, 44);
    __builtin_amdgcn_sched_barrier(0);

    // ---- kh = 1 ----
    LOADS(0, bof1, 0);
    LOADS(1, bof1, 1); __builtin_amdgcn_sched_barrier(0); MM(0, 0);
    LOADS(0, bof1, 2); __builtin_amdgcn_sched_barrier(0); MM(1, 1);
    __builtin_amdgcn_sched_barrier(0);                    MM(0, 2);
#undef MM
#undef LOADS
  }
#undef STG

  // epilogue: C row = o-within-32 = (r&3)+8*(r>>2)+4*h5 ; col = x = l31
#pragma unroll
  for (int rr = 0; rr < 2; ++rr) {
    const int h = h0 + hp * 2 + rr;
#pragma unroll
    for (int io = 0; io < 2; ++io) {
#pragma unroll
      for (int r = 0; r < 16; ++r) {
        const int orow = (r & 3) + ((r >> 2) << 3) + (h5 << 2);
        const int oG = oBase + (io << 5) + orow;
        out[(((size_t)(b * 256 + oG)) * 64 + h) * 64 + x0w + l31] =
            acc[rr][io][r] + bias[oG];
      }
    }
  }
}

extern "C" void kernel_launch(void* const* d_in, const int* in_sizes, int n_in,
                              void* d_out, int out_size, void* d_ws, size_t ws_size,
                              hipStream_t stream) {
  (void)in_sizes; (void)n_in; (void)out_size; (void)ws_size;
  const float* X     = (const float*)d_in[0];
  const float* convw = (const float*)d_in[1];
  const float* convb = (const float*)d_in[2];
  const float* core1 = (const float*)d_in[3];
  const float* core2 = (const float*)d_in[4];
  const float* core3 = (const float*)d_in[5];
  float* out = (float*)d_out;
  char*  ws  = (char*)d_ws;

  short* Xp   = (short*)ws;
  short* W9   = (short*)(ws + OFF_W9);
  float* bias = (float*)(ws + OFF_BIAS);

  // fused weights+pad (no memset: k_prep writes every Xpad granule)
  k_prep<<<4480, 256, 0, stream>>>(X, core1, core2, core3, convw, convb,
                                   Xp, W9, bias);
  k_gemm<<<dim3(8, 4, 8), 512, 0, stream>>>(Xp, W9, bias, out);
}

// Round 9
// 150.358 us; speedup vs baseline: 1.0203x; 1.0203x over previous
//
#include <hip/hip_runtime.h>
#include <hip/hip_bf16.h>
#include <stdint.h>

typedef __attribute__((ext_vector_type(8))) short short8;
typedef __attribute__((ext_vector_type(4))) float f32x4;

// ---------------- ws layout (bytes) ----------------
// Xpad granules: [b(8)][cb(8)][y(66)][x(66)][slot(4)] * 16B = 17,842,176
#define XP_BYTES   17842176
#define XP_PAD     1024
#define OFF_W9     (XP_BYTES + XP_PAD)            // 17,843,200
#define W9_BYTES   (8*9*256*32*2)                 // 1,179,648
#define OFF_BIAS   (OFF_W9 + W9_BYTES)

__device__ __forceinline__ short f2bf(float f) {
  __hip_bfloat16 h = __float2bfloat16(f);
  return *reinterpret_cast<short*>(&h);
}

__device__ __forceinline__ void gl_lds16(const void* g, void* l) {
  __builtin_amdgcn_global_load_lds(
      (const __attribute__((address_space(1))) void*)g,
      (__attribute__((address_space(3))) void*)l, 16, 0, 0);
}

// Fused prep (r6 proven version): blocks [0,256) weights; [256,4480) pad rows.
__global__ void k_prep(const float* __restrict__ X,
                       const float* __restrict__ core1,
                       const float* __restrict__ core2,
                       const float* __restrict__ core3,
                       const float* __restrict__ convw,
                       const float* __restrict__ convb,
                       short* __restrict__ Xp,
                       short* __restrict__ W9, float* __restrict__ bias) {
  if (blockIdx.x < 256) {
    // ---------------- weights ----------------
    __shared__ float H2s[1024];   // [u(16)][j(8)][k(8)]
    __shared__ float red[256];
    const int o = blockIdx.x, c = threadIdx.x;
    const int a = o >> 6, c2 = (o >> 3) & 7, d = o & 7;
#pragma unroll
    for (int p = 0; p < 4; ++p) {
      int idx = c + (p << 8);
      int k = idx & 7, j = (idx >> 3) & 7, u = idx >> 6;
      float s = 0.f;
#pragma unroll
      for (int v = 0; v < 16; ++v)
        s += core2[(c2 * 16 + v) * 128 + u * 8 + j] * core3[d * 128 + v * 8 + k];
      H2s[idx] = s;
    }
    __syncthreads();
    const int i = c >> 6, j = (c >> 3) & 7, k = c & 7;
    float Wr[16];
#pragma unroll
    for (int r = 0; r < 16; ++r) Wr[r] = 0.f;
    for (int u = 0; u < 16; ++u) {
      float h = H2s[u * 64 + j * 8 + k];
      const float* c1 = core1 + (a * 16 + u) * 64 + i;
#pragma unroll
      for (int r = 0; r < 16; ++r) Wr[r] += c1[r * 4] * h;
    }
    // W9 layout: [cb][t][o(256)][slot(4)][8], slot = g ^ (o&3)
    const int cb = c >> 5, cl = c & 31, g = cl >> 3, pos = cl & 7;
    const int gslot = g ^ (o & 3);
#pragma unroll
    for (int t = 0; t < 9; ++t) {
      float s = 0.f;
#pragma unroll
      for (int r = 0; r < 16; ++r) s += Wr[r] * convw[r * 9 + t];
      W9[((size_t)((cb * 9 + t) * 256 + o)) * 32 + gslot * 8 + pos] = f2bf(s);
    }
    float s = 0.f;
#pragma unroll
    for (int r = 0; r < 16; ++r) s += Wr[r] * convb[r];
    red[c] = s;
    __syncthreads();
    for (int st = 128; st > 0; st >>= 1) {
      if (c < st) red[c] += red[c + st];
      __syncthreads();
    }
    if (c == 0) bias[o] = red[0];
    return;
  }
  // ---------------- pad+transpose (LDS-staged row, contiguous stores) ------
  const int p = blockIdx.x - 256;
  const int cb = p / 528, rem = p % 528;
  const int b = rem / 66, yp = rem % 66;
  const int t = threadIdx.x;
  short* rowp = Xp + ((size_t)((b * 8 + cb) * 66 + yp)) * 264 * 8;
  const short8 z = (short8){0, 0, 0, 0, 0, 0, 0, 0};
  if (yp == 0 || yp == 65) {
    *(short8*)(rowp + t * 8) = z;
    if (t < 8) *(short8*)(rowp + ((256 + t) * 8)) = z;
    return;
  }
  __shared__ __align__(16) short Ls[264 * 8];   // one padded row, 4224 B
  *(short8*)&Ls[t * 8] = z;
  if (t < 8) *(short8*)&Ls[(256 + t) * 8] = z;
  __syncthreads();
  const int x = t & 63, sub = t >> 6, xp = x + 1, y = yp - 1;
  const int gslot = sub ^ ((xp >> 1) & 3);
  const float* src = X + ((size_t)(b * 256 + cb * 32 + sub * 8) * 64 + y) * 64 + x;
  short8 v;
#pragma unroll
  for (int k = 0; k < 8; ++k) v[k] = f2bf(src[(size_t)k * 4096]);
  *(short8*)&Ls[(xp * 4 + gslot) * 8] = v;
  __syncthreads();
  *(short8*)(rowp + t * 8) = *(const short8*)&Ls[t * 8];
  if (t < 8) *(short8*)(rowp + (256 + t) * 8) = *(const short8*)&Ls[(256 + t) * 8];
}

// main GEMM: out[b,o,h,w] = bias[o] + sum_{c,t} K9[o,c,t]*Xpad[b,c,h+dy,w+dx]
// TLP round: block = 4h x 64o x 32x, 256 thr (4 waves), wave = 1h x 64o x 32x
// (io=4 -> 0.25 LDS reads/MFMA). X tile 6 rows x 48 cols = 18.4KB,
// double-buffered = 36.9KB/block -> 3 blocks/CU = 3 waves/SIMD (the axis no
// schedule variant changed; r8 showed ~50% of wall is all-pipes-idle).
// 1 barrier/cb; stage(cb+1) in thirds, af batches (12 b128/dx) issued BEFORE
// each third so af waits are counted vmcnt(24)/vmcnt(6) - prefetch never
// drains mid-cb. Peak regs ~167 (af 96 + acc 32 + bfr 24) under the 170 cap.
__global__ __launch_bounds__(256, 3) void k_gemm(
    const short* __restrict__ Xp, const short* __restrict__ W9,
    const float* __restrict__ bias, float* __restrict__ out) {
  __shared__ __align__(16) short XL[2][9216];   // 2 x 18,432 B

  const int tid  = threadIdx.x;
  const int lane = tid & 63;
  const int wv   = tid >> 6;           // 4 waves; wave = output row h0+wv
  const int l15  = lane & 15;
  const int gl   = lane >> 4;          // k-granule 0..3
  const int h0    = blockIdx.x << 2;   // 4 output rows / block
  const int o4    = blockIdx.y & 3;
  const int xh    = blockIdx.y >> 2;
  const int oBase = o4 << 6;           // 64 out-channels / block
  const int x0    = xh << 5;           // 32 x / block
  const int xlo   = xh ? 18 : 0;       // staged col range [xlo, xlo+48)
  const int b     = blockIdx.z;

  // LDS short-offsets for bfr: row wv+dy, col x = x0+l15+dx (+512 for ip=1;
  // swizzle key (x>>1)&3 invariant under +16)
  int xoff[3][3];
#pragma unroll
  for (int dy = 0; dy < 3; ++dy)
#pragma unroll
    for (int dx = 0; dx < 3; ++dx) {
      const int x = x0 + l15 + dx;
      xoff[dy][dx] = ((wv + dy) * 192 + (x - xlo) * 4 + (gl ^ ((x >> 1) & 3))) * 8;
    }
  // af per-lane base into W9 (shorts); per (cb,t,io): +cb*73728+t*8192+io*512
  const int laneW = (oBase + l15) * 32 + ((gl ^ (l15 & 3)) << 3);

  f32x4 acc[4][2];
#pragma unroll
  for (int io = 0; io < 4; ++io)
#pragma unroll
    for (int ip = 0; ip < 2; ++ip)
      acc[io][ip] = (f32x4){0.f, 0.f, 0.f, 0.f};

  // stage: 6 rows x 3 chunks of 1KB (chunk = 64 granules, contiguous)
#define STG(CB, BUF, QLO, QHI)                                                \
  {                                                                           \
    _Pragma("unroll 1")                                                       \
    for (int q = (QLO) + wv; q < (QHI); q += 4) {                             \
      const int row = q / 3, cc = q % 3;                                      \
      const short* src = Xp +                                                 \
          (((size_t)((b << 3) + (CB)) * 66 + h0 + row) * 264                  \
           + (xlo << 2) + (cc << 6) + lane) * 8;                              \
      gl_lds16(src, &XL[BUF][(q << 9) + (lane << 3)]);                        \
    }                                                                         \
  }

#define AF(DST, CB, DX)                                                       \
  {                                                                           \
    const short* Wc = W9 + (size_t)(CB) * 73728 + laneW;                      \
    _Pragma("unroll")                                                         \
    for (int dy = 0; dy < 3; ++dy)                                            \
      _Pragma("unroll")                                                       \
      for (int io = 0; io < 4; ++io)                                          \
        DST[dy][io] = *(const short8*)&Wc[(dy * 3 + (DX)) * 8192 + io * 512]; \
  }

#define BFR(DX)                                                               \
  {                                                                           \
    _Pragma("unroll")                                                         \
    for (int dy = 0; dy < 3; ++dy)                                            \
      _Pragma("unroll")                                                       \
      for (int ip = 0; ip < 2; ++ip)                                          \
        bfr[dy][ip] = *(const short8*)&XLc[xoff[dy][DX] + (ip << 9)];         \
  }

#define MM(AFR)                                                               \
  {                                                                           \
    __builtin_amdgcn_s_setprio(1);                                            \
    _Pragma("unroll")                                                         \
    for (int dy = 0; dy < 3; ++dy)                                            \
      _Pragma("unroll")                                                       \
      for (int io = 0; io < 4; ++io)                                          \
        _Pragma("unroll")                                                     \
        for (int ip = 0; ip < 2; ++ip)                                        \
          acc[io][ip] = __builtin_amdgcn_mfma_f32_16x16x32_bf16(              \
              AFR[dy][io], bfr[dy][ip], acc[io][ip], 0, 0, 0);                \
    __builtin_amdgcn_s_setprio(0);                                            \
  }

  STG(0, 0, 0, 18);   // prologue

  short8 af0[3][4], af1[3][4], af2[3][4];
  short8 bfr[3][2];

  for (int cb = 0; cb < 8; ++cb) {
    AF(af0, cb, 0);                    // pre-barrier: folds into barrier drain
    __builtin_amdgcn_sched_barrier(0);
    __syncthreads();                   // XL[cb&1] ready (staged during cb-1)

    const short* XLc = &XL[cb & 1][0];
    const int nb = (cb + 1) & 1;

    if (cb < 7) STG(cb + 1, nb, 0, 6);     // stage third 0
    __builtin_amdgcn_sched_barrier(0);
    AF(af1, cb, 1);                        // af dx1 (before third 1)
    __builtin_amdgcn_sched_barrier(0);
    if (cb < 7) STG(cb + 1, nb, 6, 12);    // stage third 1
    __builtin_amdgcn_sched_barrier(0);

    BFR(0); MM(af0);                       // dx0 (af0 drained at barrier)

    AF(af2, cb, 2);                        // af dx2 (before third 2)
    __builtin_amdgcn_sched_barrier(0);
    if (cb < 7) STG(cb + 1, nb, 12, 18);   // stage third 2
    __builtin_amdgcn_sched_barrier(0);

    BFR(1); MM(af1);                       // dx1: wait = vmcnt(24), counted
    BFR(2); MM(af2);                       // dx2: wait = vmcnt(6), counted
  }
#undef MM
#undef BFR
#undef AF
#undef STG

  // epilogue (r6 output mapping): oG = oBase+io*16+gl*4+r, col = ip*16+l15
  const int h = h0 + wv;
#pragma unroll
  for (int io = 0; io < 4; ++io) {
#pragma unroll
    for (int r = 0; r < 4; ++r) {
      const int oG = oBase + (io << 4) + (gl << 2) + r;
      const float bv = bias[oG];
      float* op = out + (((size_t)((b << 8) + oG)) << 12) + (h << 6) + x0;
#pragma unroll
      for (int ip = 0; ip < 2; ++ip)
        op[(ip << 4) + l15] = acc[io][ip][r] + bv;
    }
  }
}

extern "C" void kernel_launch(void* const* d_in, const int* in_sizes, int n_in,
                              void* d_out, int out_size, void* d_ws, size_t ws_size,
                              hipStream_t stream) {
  (void)in_sizes; (void)n_in; (void)out_size; (void)ws_size;
  const float* X     = (const float*)d_in[0];
  const float* convw = (const float*)d_in[1];
  const float* convb = (const float*)d_in[2];
  const float* core1 = (const float*)d_in[3];
  const float* core2 = (const float*)d_in[4];
  const float* core3 = (const float*)d_in[5];
  float* out = (float*)d_out;
  char*  ws  = (char*)d_ws;

  short* Xp   = (short*)ws;
  short* W9   = (short*)(ws + OFF_W9);
  float* bias = (float*)(ws + OFF_BIAS);

  // fused weights+pad (no memset: k_prep writes every Xpad granule)
  k_prep<<<4480, 256, 0, stream>>>(X, core1, core2, core3, convw, convb,
                                   Xp, W9, bias);
  k_gemm<<<dim3(16, 8, 8), 256, 0, stream>>>(Xp, W9, bias, out);
}

// Round 10
// 130.597 us; speedup vs baseline: 1.1747x; 1.1513x over previous
//
#include <hip/hip_runtime.h>
#include <hip/hip_bf16.h>
#include <stdint.h>

typedef __attribute__((ext_vector_type(8))) short short8;
typedef __attribute__((ext_vector_type(4))) float f32x4;

// ---------------- ws layout (bytes) ----------------
// Xpad granules: [b(8)][cb(8)][y(66)][x(66)][slot(4)] * 16B = 17,842,176
//   slot = sub ^ ((xp>>1)&3)  (bank key x&7 -> conflict-free b128 reads)
#define XP_BYTES   17842176
#define XP_PAD     1024
#define OFF_W9     (XP_BYTES + XP_PAD)            // 17,843,200
#define W9_BYTES   (8*9*256*32*2)                 // 1,179,648
#define OFF_BIAS   (OFF_W9 + W9_BYTES)

__device__ __forceinline__ short f2bf(float f) {
  __hip_bfloat16 h = __float2bfloat16(f);
  return *reinterpret_cast<short*>(&h);
}

__device__ __forceinline__ void gl_lds16(const void* g, void* l) {
  __builtin_amdgcn_global_load_lds(
      (const __attribute__((address_space(1))) void*)g,
      (__attribute__((address_space(3))) void*)l, 16, 0, 0);
}

// Fused prep. Blocks [0,512): pad+transpose, one block per (b,cb,row-octant),
// 8-9 rows each (fat blocks: amortize launch/setup; r9's 4224 tiny blocks
// were latency-bound). Blocks [512,768): weight prep, one per o.
__global__ void k_prep(const float* __restrict__ X,
                       const float* __restrict__ core1,
                       const float* __restrict__ core2,
                       const float* __restrict__ core3,
                       const float* __restrict__ convw,
                       const float* __restrict__ convb,
                       short* __restrict__ Xp,
                       short* __restrict__ W9, float* __restrict__ bias) {
  if (blockIdx.x < 512) {
    // ---------------- pad+transpose ----------------
    const int p = blockIdx.x;
    const int bc = p >> 3, g = p & 7;
    const int b = bc >> 3, cb = bc & 7;
    const int y0 = (g < 2) ? g * 9 : 18 + (g - 2) * 8;   // rows [y0, y0+ny)
    const int ny = (g < 2) ? 9 : 8;                      // 9+9+8*6 = 66
    const int t = threadIdx.x;
    const short8 z = (short8){0, 0, 0, 0, 0, 0, 0, 0};
    __shared__ __align__(16) short Ls[264 * 8];   // one padded row, 4224 B
    // border granules (xp=0 -> 0..3, xp=65 -> 260..263) zeroed ONCE:
    // interior writes below only touch granules 4..259.
    if (t < 8) {
      const int gid = (t < 4) ? t : 260 + (t - 4);
      *(short8*)&Ls[gid * 8] = z;
    }
    const int x = t & 63, sub = t >> 6, xp = x + 1;
    const int gslot = sub ^ ((xp >> 1) & 3);
    for (int r = 0; r < ny; ++r) {
      const int yp = y0 + r;
      short* rowp = Xp + ((size_t)((b * 8 + cb) * 66 + yp)) * 264 * 8;
      if (yp == 0 || yp == 65) {        // uniform branch per block-iteration
        *(short8*)(rowp + t * 8) = z;
        if (t < 8) *(short8*)(rowp + (256 + t) * 8) = z;
        continue;
      }
      const int y = yp - 1;
      const float* src =
          X + ((size_t)(b * 256 + cb * 32 + sub * 8) * 64 + y) * 64 + x;
      short8 v;
#pragma unroll
      for (int k = 0; k < 8; ++k) v[k] = f2bf(src[(size_t)k * 4096]);
      __syncthreads();                  // prev row's write-out done
      *(short8*)&Ls[(xp * 4 + gslot) * 8] = v;
      __syncthreads();
      // contiguous write-out: full 64B sectors, no RMW
      *(short8*)(rowp + t * 8) = *(const short8*)&Ls[t * 8];
      if (t < 8)
        *(short8*)(rowp + (256 + t) * 8) = *(const short8*)&Ls[(256 + t) * 8];
    }
    return;
  }
  // ---------------- weights ----------------
  __shared__ float H2s[1024];   // [u(16)][j(8)][k(8)]
  __shared__ float red[256];
  const int o = blockIdx.x - 512, c = threadIdx.x;
  const int a = o >> 6, c2 = (o >> 3) & 7, d = o & 7;
#pragma unroll
  for (int p = 0; p < 4; ++p) {
    int idx = c + (p << 8);
    int k = idx & 7, j = (idx >> 3) & 7, u = idx >> 6;
    float s = 0.f;
#pragma unroll
    for (int v = 0; v < 16; ++v)
      s += core2[(c2 * 16 + v) * 128 + u * 8 + j] * core3[d * 128 + v * 8 + k];
    H2s[idx] = s;
  }
  __syncthreads();
  const int i = c >> 6, j = (c >> 3) & 7, k = c & 7;
  float Wr[16];
#pragma unroll
  for (int r = 0; r < 16; ++r) Wr[r] = 0.f;
  for (int u = 0; u < 16; ++u) {
    float h = H2s[u * 64 + j * 8 + k];
    const float* c1 = core1 + (a * 16 + u) * 64 + i;
#pragma unroll
    for (int r = 0; r < 16; ++r) Wr[r] += c1[r * 4] * h;
  }
  // W9 layout: [cb][t][o(256)][slot(4)][8], slot = g ^ (o&3)
  const int cb = c >> 5, cl = c & 31, gg = cl >> 3, pos = cl & 7;
  const int gslot = gg ^ (o & 3);
#pragma unroll
  for (int t = 0; t < 9; ++t) {
    float s = 0.f;
#pragma unroll
    for (int r = 0; r < 16; ++r) s += Wr[r] * convw[r * 9 + t];
    W9[((size_t)((cb * 9 + t) * 256 + o)) * 32 + gslot * 8 + pos] = f2bf(s);
  }
  float s = 0.f;
#pragma unroll
  for (int r = 0; r < 16; ++r) s += Wr[r] * convb[r];
  red[c] = s;
  __syncthreads();
  for (int st = 128; st > 0; st >>= 1) {
    if (c < st) red[c] += red[c + st];
    __syncthreads();
  }
  if (c == 0) bias[o] = red[0];
}

// main GEMM (r6-proven version, measured 44.1us): out = bias + sum K9*Xpad
// Block = 16 rows x 32 o, 512 threads (8 waves), wave = 2 rows x 32 o.
// Grid (4,8,8) = 256 blocks = 1/CU -> 2 waves/SIMD. X-only LDS double buffer.
// One barrier per cb; stage(cb+1) issued after it, drained at next barrier.
// Inner loop: 12 steps (3 dx x 4 ip), register-double-buffered bfr prefetch
// overlapped with 12-MFMA setprio clusters.
__global__ __launch_bounds__(512, 1) void k_gemm(
    const short* __restrict__ Xp, const short* __restrict__ W9,
    const float* __restrict__ bias, float* __restrict__ out) {
  __shared__ __align__(16) short XL[2][38400];  // 2 x 76.8 KB = 153.6 KB

  const int tid  = threadIdx.x;
  const int lane = tid & 63;
  const int wv   = tid >> 6;           // 8 waves
  const int l15  = lane & 15;
  const int gl   = lane >> 4;          // k-granule 0..3
  const int h0    = blockIdx.x << 4;   // 16 output rows / block
  const int oBase = blockIdx.y << 5;   // 32 out-channels / block
  const int b     = blockIdx.z;
  const int r0    = wv << 1;           // wave's local output-row base (0..14)

  // precomputed LDS short-offsets: xoff[xr][dx] for row r0+xr, x=l15+dx (+16ip)
  int xoff[4][3];
#pragma unroll
  for (int xr = 0; xr < 4; ++xr)
#pragma unroll
    for (int dx = 0; dx < 3; ++dx)
      xoff[xr][dx] = ((r0 + xr) * 66 + l15 + dx) * 32 +
                     ((gl ^ (((l15 + dx) >> 1) & 3)) << 3);

  // af lane offset (shorts) into W9: per (cb,t,io) add cb*73728+t*8192+io*512
  const int laneW = (oBase + l15) * 32 + ((gl ^ (l15 & 3)) << 3);

  f32x4 acc[2][2][4];
#pragma unroll
  for (int rr = 0; rr < 2; ++rr)
#pragma unroll
    for (int io = 0; io < 2; ++io)
#pragma unroll
      for (int ip = 0; ip < 4; ++ip)
        acc[rr][io][ip] = (f32x4){0.f, 0.f, 0.f, 0.f};

  // stage helper: 18 padded rows x 264 granules = 76,032 B -> 75 x 1KB chunks
  // (chunk 74 over-reads 768 B of the next slab: in-bounds, unused)
#define STAGE(CB, BUF)                                                     \
  {                                                                        \
    const size_t xb = ((size_t)(((b << 3) + (CB)) * 66 + h0) * 66) << 5;   \
    _Pragma("unroll 1")                                                    \
    for (int q = wv; q < 75; q += 8)                                       \
      gl_lds16(Xp + xb + (q << 9) + (lane << 3), &XL[BUF][q << 9]);        \
  }

  STAGE(0, 0);   // prologue

  for (int cb = 0; cb < 8; ++cb) {
    // af preload: 18 global b128, issued BEFORE the barrier so the barrier's
    // drain covers them (no vmcnt wait can ever drain the next stage queue)
    const short* Wc = W9 + cb * 73728 + laneW;
    short8 af[9][2];
#pragma unroll
    for (int t = 0; t < 9; ++t)
#pragma unroll
      for (int io = 0; io < 2; ++io)
        af[t][io] = *(const short8*)&Wc[t * 8192 + (io << 9)];
    __builtin_amdgcn_sched_barrier(0);

    __syncthreads();   // drains stage(cb) (+af); XL[cb&1] ready

    if (cb < 7) STAGE(cb + 1, (cb + 1) & 1);
    __builtin_amdgcn_sched_barrier(0);

    const short* XLc = &XL[cb & 1][0];
    short8 bfr[2][4];  // [regbuf][xr], static-indexed (full unroll)

#define LOADS(BUF, DX, IP)                                                 \
  {                                                                        \
    _Pragma("unroll")                                                      \
    for (int xr = 0; xr < 4; ++xr)                                         \
      bfr[BUF][xr] = *(const short8*)&XLc[xoff[xr][DX] + ((IP) << 9)];     \
  }

    LOADS(0, 0, 0);    // step-0 fragments
#pragma unroll
    for (int s = 0; s < 12; ++s) {
      const int dx = s >> 2, ip = s & 3, buf = s & 1;
      if (s < 11) LOADS(buf ^ 1, (s + 1) >> 2, (s + 1) & 3);
      __builtin_amdgcn_sched_barrier(0);   // reads issued before MFMA cluster
      __builtin_amdgcn_s_setprio(1);
#pragma unroll
      for (int dy = 0; dy < 3; ++dy) {
        const int t = dy * 3 + dx;
#pragma unroll
        for (int io = 0; io < 2; ++io) {
          acc[0][io][ip] = __builtin_amdgcn_mfma_f32_16x16x32_bf16(
              af[t][io], bfr[buf][dy], acc[0][io][ip], 0, 0, 0);
          acc[1][io][ip] = __builtin_amdgcn_mfma_f32_16x16x32_bf16(
              af[t][io], bfr[buf][dy + 1], acc[1][io][ip], 0, 0, 0);
        }
      }
      __builtin_amdgcn_s_setprio(0);
    }
#undef LOADS
  }
#undef STAGE

  // epilogue
#pragma unroll
  for (int rr = 0; rr < 2; ++rr) {
    const int h = h0 + r0 + rr;
#pragma unroll
    for (int io = 0; io < 2; ++io) {
#pragma unroll
      for (int r = 0; r < 4; ++r) {
        const int oG = oBase + (io << 4) + (gl << 2) + r;
        const float bv = bias[oG];
        float* op = out + (((size_t)((b << 8) + oG)) << 12) + (h << 6);
#pragma unroll
        for (int ip = 0; ip < 4; ++ip)
          op[(ip << 4) + l15] = acc[rr][io][ip][r] + bv;
      }
    }
  }
}

extern "C" void kernel_launch(void* const* d_in, const int* in_sizes, int n_in,
                              void* d_out, int out_size, void* d_ws, size_t ws_size,
                              hipStream_t stream) {
  (void)in_sizes; (void)n_in; (void)out_size; (void)ws_size;
  const float* X     = (const float*)d_in[0];
  const float* convw = (const float*)d_in[1];
  const float* convb = (const float*)d_in[2];
  const float* core1 = (const float*)d_in[3];
  const float* core2 = (const float*)d_in[4];
  const float* core3 = (const float*)d_in[5];
  float* out = (float*)d_out;
  char*  ws  = (char*)d_ws;

  short* Xp   = (short*)ws;
  short* W9   = (short*)(ws + OFF_W9);
  float* bias = (float*)(ws + OFF_BIAS);

  // fused pad(512 fat blocks)+weights(256) ; no memset (pad writes all)
  k_prep<<<768, 256, 0, stream>>>(X, core1, core2, core3, convw, convb,
                                  Xp, W9, bias);
  k_gemm<<<dim3(4, 8, 8), 512, 0, stream>>>(Xp, W9, bias, out);
}